// Round 5
// baseline (3180.458 us; speedup 1.0000x reference)
//
#include <hip/hip_runtime.h>
#include <stdint.h>

#define IN_DIM 2020
#define HDIM 20
#define EPSV 1e-5f
#define SCAN_BS 1024

// ---------------- degree (by src, float) + in-count (by dst, int), one edge pass ----------------

__global__ void count_both(const int* __restrict__ src, const int* __restrict__ dst,
                           float* __restrict__ deg, int* __restrict__ cnt, int E) {
  int e = blockIdx.x * blockDim.x + threadIdx.x;
  if (e < E) {
    atomicAdd(&deg[src[e]], 1.0f);
    atomicAdd(&cnt[dst[e]], 1);
  }
}

__global__ void make_dis(float* deg, int n) {
  int i = blockIdx.x * blockDim.x + threadIdx.x;
  if (i < n) { float d = deg[i]; deg[i] = d > 0.5f ? rsqrtf(d) : 0.0f; }
}

// ---------------- CSR build (by dst) ----------------

__global__ __launch_bounds__(SCAN_BS) void scan1(const int* __restrict__ cnt,
                                                 int* __restrict__ scanned,
                                                 int* __restrict__ bsums, int n) {
  __shared__ int sm[SCAN_BS];
  int i = blockIdx.x * SCAN_BS + threadIdx.x;
  int v = (i < n) ? cnt[i] : 0;
  sm[threadIdx.x] = v;
  __syncthreads();
  for (int off = 1; off < SCAN_BS; off <<= 1) {
    int t = (threadIdx.x >= (unsigned)off) ? sm[threadIdx.x - off] : 0;
    __syncthreads();
    sm[threadIdx.x] += t;
    __syncthreads();
  }
  if (i < n) scanned[i] = sm[threadIdx.x];
  if (threadIdx.x == SCAN_BS - 1) bsums[blockIdx.x] = sm[SCAN_BS - 1];
}

__global__ __launch_bounds__(SCAN_BS) void scan2(int* __restrict__ bsums, int nb) {
  __shared__ int sm[SCAN_BS];
  int i = threadIdx.x;
  sm[i] = (i < nb) ? bsums[i] : 0;
  __syncthreads();
  for (int off = 1; off < SCAN_BS; off <<= 1) {
    int t = (i >= off) ? sm[i - off] : 0;
    __syncthreads();
    sm[i] += t;
    __syncthreads();
  }
  if (i < nb) bsums[i] = sm[i];
}

__global__ void scan3(const int* __restrict__ scanned, const int* __restrict__ bsums,
                      const int* __restrict__ cnt, int* __restrict__ rowptr,
                      int* __restrict__ cursor, int n) {
  int i = blockIdx.x * blockDim.x + threadIdx.x;
  if (i >= n) return;
  int b = i >> 10;  // i / SCAN_BS
  int off = (b > 0) ? bsums[b - 1] : 0;
  int incl = scanned[i] + off;
  rowptr[i + 1] = incl;
  cursor[i] = incl - cnt[i];
  if (i == 0) rowptr[0] = 0;
}

// fold norm into payload: csr[pos] = {src, bits(-dis[src]*dis[dst])}
__global__ void place_edges(const int* __restrict__ src, const int* __restrict__ dst,
                            const float* __restrict__ dis, int* __restrict__ cursor,
                            int2* __restrict__ csr, int E) {
  int e = blockIdx.x * blockDim.x + threadIdx.x;
  if (e >= E) return;
  int s = src[e], d = dst[e];
  float w = -dis[s] * dis[d];
  int pos = atomicAdd(&cursor[d], 1);
  csr[pos] = make_int2(s, __float_as_int(w));
}

// ---------------- layer-0 projection GEMM: Y(N x 64) = X(N x 2020) @ [W0|W1|W2](2020 x 60) ----------------
// 128 rows x 64 cols per block, 256 threads, thread tile 8x4, KC=20 (2020 = 101*20)

__global__ __launch_bounds__(256) void gemm0(const float* __restrict__ X,
                                             const float* __restrict__ W0,
                                             float* __restrict__ Y, int N) {
  __shared__ float lx[20][136];
  __shared__ float lw[20][68];
  int tid = threadIdx.x;
  for (int i = tid; i < 20 * 136; i += 256) ((float*)lx)[i] = 0.f;
  for (int i = tid; i < 20 * 68; i += 256) ((float*)lw)[i] = 0.f;

  int row0 = blockIdx.x * 128;
  int tr = tid >> 4, tc = tid & 15;
  int r0 = tr * 8, c0 = tc * 4;
  float4 acc[8];
#pragma unroll
  for (int i = 0; i < 8; i++) acc[i] = make_float4(0.f, 0.f, 0.f, 0.f);
  __syncthreads();

  for (int kb = 0; kb < 101; ++kb) {
    int kbase = kb * 20;
    for (int i = tid; i < 1200; i += 256) {
      int k = i / 60, c = i % 60;
      int kk = c / 20, h = c % 20;
      lw[k][c] = W0[kk * (IN_DIM * HDIM) + (kbase + k) * HDIM + h];
    }
    for (int i = tid; i < 640; i += 256) {
      int r = i / 5, f4 = i % 5;
      int row = row0 + r;
      if (row < N) {
        float4 v = *(const float4*)(X + (size_t)row * IN_DIM + kbase + f4 * 4);
        int k = f4 * 4;
        lx[k + 0][r] = v.x; lx[k + 1][r] = v.y; lx[k + 2][r] = v.z; lx[k + 3][r] = v.w;
      }
    }
    __syncthreads();
#pragma unroll
    for (int k = 0; k < 20; ++k) {
      float4 wv = *(const float4*)&lw[k][c0];
      float4 xa = *(const float4*)&lx[k][r0];
      float4 xb = *(const float4*)&lx[k][r0 + 4];
      float xs[8] = {xa.x, xa.y, xa.z, xa.w, xb.x, xb.y, xb.z, xb.w};
#pragma unroll
      for (int rr = 0; rr < 8; rr++) {
        acc[rr].x += xs[rr] * wv.x;
        acc[rr].y += xs[rr] * wv.y;
        acc[rr].z += xs[rr] * wv.z;
        acc[rr].w += xs[rr] * wv.w;
      }
    }
    __syncthreads();
  }
#pragma unroll
  for (int i = 0; i < 8; i++) {
    int row = row0 + r0 + i;
    if (row < N) *(float4*)(Y + (size_t)row * 64 + c0) = acc[i];
  }
}

// ---------------- gather propagation (CSR, float4 lanes) ----------------
// prop20: 5 lanes per node, lane q gathers float4 x[src][4q..4q+3]
__global__ __launch_bounds__(320) void prop20_csr(const float* __restrict__ x,
                                                  const int* __restrict__ rowptr,
                                                  const int2* __restrict__ csr,
                                                  float* __restrict__ out, int n) {
  int t = blockIdx.x * 320 + threadIdx.x;
  int node = t / 5, q = t - node * 5;
  if (node >= n) return;
  int beg = rowptr[node], end = rowptr[node + 1];
  float4 a = make_float4(0.f, 0.f, 0.f, 0.f);
  for (int j = beg; j < end; ++j) {
    int2 e = csr[j];
    float w = __int_as_float(e.y);
    float4 v = *(const float4*)(x + (size_t)e.x * HDIM + q * 4);
    a.x += w * v.x; a.y += w * v.y; a.z += w * v.z; a.w += w * v.w;
  }
  *(float4*)(out + (size_t)node * HDIM + q * 4) = a;
}

// layer-0 dual prop: 10 lanes per node; q<5 -> Y cols 20..39 into S1, q>=5 -> Y cols 40..59 into S2
__global__ __launch_bounds__(320) void prop40_csr(const float* __restrict__ Y,
                                                  const int* __restrict__ rowptr,
                                                  const int2* __restrict__ csr,
                                                  float* __restrict__ S1,
                                                  float* __restrict__ S2, int n) {
  int t = blockIdx.x * 320 + threadIdx.x;
  int node = t / 10, q = t - node * 10;
  if (node >= n) return;
  int beg = rowptr[node], end = rowptr[node + 1];
  int col = 20 + q * 4;  // 20..56
  float4 a = make_float4(0.f, 0.f, 0.f, 0.f);
  for (int j = beg; j < end; ++j) {
    int2 e = csr[j];
    float w = __int_as_float(e.y);
    float4 v = *(const float4*)(Y + (size_t)e.x * 64 + col);
    a.x += w * v.x; a.y += w * v.y; a.z += w * v.z; a.w += w * v.w;
  }
  float* op = (q < 5) ? (S1 + (size_t)node * HDIM + q * 4)
                      : (S2 + (size_t)node * HDIM + (q - 5) * 4);
  *(float4*)op = a;
}

// ---------------- fused per-node epilogues ----------------

__device__ __forceinline__ float bnrelu(float c, float g, float b, float m, float v) {
  return fmaxf((c - m) * rsqrtf(v + EPSV) * g + b, 0.0f);
}

__device__ __forceinline__ float softmax_w(const float* fw, int idx) {
  float f0 = fw[0], f1 = fw[1], f2 = fw[2], f3 = fw[3];
  float mx = fmaxf(fmaxf(f0, f1), fmaxf(f2, f3));
  float e0 = expf(f0 - mx), e1 = expf(f1 - mx), e2 = expf(f2 - mx), e3 = expf(f3 - mx);
  float s = e0 + e1 + e2 + e3;
  float e[4] = {e0, e1, e2, e3};
  return e[idx] / s;
}

// layer 0: cheb0 = Y0 + P1 + 2*P2 - Y2 + b0 ; x = relu(bn(cheb0)) ; emb = w0*x
__global__ void layer0_fused(const float* __restrict__ Y, const float* __restrict__ P1,
                             const float* __restrict__ P2, const float* __restrict__ b0,
                             const float* __restrict__ bg, const float* __restrict__ bb,
                             const float* __restrict__ bm, const float* __restrict__ bv,
                             const float* __restrict__ fw, float* __restrict__ x,
                             float* __restrict__ emb, int n) {
  int i = blockIdx.x * blockDim.x + threadIdx.x;
  if (i >= n) return;
  float w0 = softmax_w(fw, 0);
#pragma unroll
  for (int j = 0; j < 5; j++) {
    float4 y0 = *(const float4*)(Y + (size_t)i * 64 + j * 4);
    float4 y2 = *(const float4*)(Y + (size_t)i * 64 + 40 + j * 4);
    float4 p1 = *(const float4*)(P1 + (size_t)i * HDIM + j * 4);
    float4 p2 = *(const float4*)(P2 + (size_t)i * HDIM + j * 4);
    float4 bias = *(const float4*)(b0 + j * 4);
    float4 g = *(const float4*)(bg + j * 4);
    float4 be = *(const float4*)(bb + j * 4);
    float4 m = *(const float4*)(bm + j * 4);
    float4 vv = *(const float4*)(bv + j * 4);
    float4 r;
    r.x = bnrelu(y0.x + p1.x + 2.f * p2.x - y2.x + bias.x, g.x, be.x, m.x, vv.x);
    r.y = bnrelu(y0.y + p1.y + 2.f * p2.y - y2.y + bias.y, g.y, be.y, m.y, vv.y);
    r.z = bnrelu(y0.z + p1.z + 2.f * p2.z - y2.z + bias.z, g.z, be.z, m.z, vv.z);
    r.w = bnrelu(y0.w + p1.w + 2.f * p2.w - y2.w + bias.w, g.w, be.w, m.w, vv.w);
    *(float4*)(x + (size_t)i * HDIM + j * 4) = r;
    float4 em = make_float4(w0 * r.x, w0 * r.y, w0 * r.z, w0 * r.w);
    *(float4*)(emb + (size_t)i * HDIM + j * 4) = em;
  }
}

// layers 1..3: z = x@W[0] + tx1@W[1] + (2*tmp - x)@W[2] + b ; bn ; relu ; + 0.7x ; emb += wi*out
__global__ __launch_bounds__(256) void layer_fused(
    const float* __restrict__ W, const float* __restrict__ bias,
    const float* __restrict__ bg, const float* __restrict__ bb,
    const float* __restrict__ bm, const float* __restrict__ bv,
    const float* __restrict__ fw, int widx, const float* __restrict__ S1,
    const float* __restrict__ S2, float* __restrict__ x, float* __restrict__ emb,
    const float* __restrict__ ow, const float* __restrict__ ob, float* __restrict__ dout,
    int last, int n) {
  __shared__ float w[1200];
  for (int i = threadIdx.x; i < 1200; i += 256) w[i] = W[i];
  __syncthreads();
  int i = blockIdx.x * blockDim.x + threadIdx.x;
  if (i >= n) return;
  float wi = softmax_w(fw, widx);

  float xv[20], t1[20], t2[20];
#pragma unroll
  for (int j = 0; j < 5; j++) {
    float4 a = *(const float4*)(x + (size_t)i * HDIM + 4 * j);
    float4 b1 = *(const float4*)(S1 + (size_t)i * HDIM + 4 * j);
    float4 c2 = *(const float4*)(S2 + (size_t)i * HDIM + 4 * j);
    xv[4 * j + 0] = a.x; xv[4 * j + 1] = a.y; xv[4 * j + 2] = a.z; xv[4 * j + 3] = a.w;
    t1[4 * j + 0] = b1.x; t1[4 * j + 1] = b1.y; t1[4 * j + 2] = b1.z; t1[4 * j + 3] = b1.w;
    t2[4 * j + 0] = 2.f * c2.x - a.x; t2[4 * j + 1] = 2.f * c2.y - a.y;
    t2[4 * j + 2] = 2.f * c2.z - a.z; t2[4 * j + 3] = 2.f * c2.w - a.w;
  }
  float4 acc[5];
#pragma unroll
  for (int j = 0; j < 5; j++) acc[j] = *(const float4*)(bias + 4 * j);
#pragma unroll
  for (int k = 0; k < 20; k++) {
    float a0 = xv[k], a1 = t1[k], a2 = t2[k];
#pragma unroll
    for (int j = 0; j < 5; j++) {
      float4 w0 = *(const float4*)&w[k * 20 + 4 * j];
      float4 w1 = *(const float4*)&w[400 + k * 20 + 4 * j];
      float4 w2 = *(const float4*)&w[800 + k * 20 + 4 * j];
      acc[j].x += a0 * w0.x + a1 * w1.x + a2 * w2.x;
      acc[j].y += a0 * w0.y + a1 * w1.y + a2 * w2.y;
      acc[j].z += a0 * w0.z + a1 * w1.z + a2 * w2.z;
      acc[j].w += a0 * w0.w + a1 * w1.w + a2 * w2.w;
    }
  }
  float o0 = 0.f, o1 = 0.f;
#pragma unroll
  for (int j = 0; j < 5; j++) {
    float4 g = *(const float4*)(bg + 4 * j);
    float4 be = *(const float4*)(bb + 4 * j);
    float4 m = *(const float4*)(bm + 4 * j);
    float4 vv = *(const float4*)(bv + 4 * j);
    float4 r;
    r.x = bnrelu(acc[j].x, g.x, be.x, m.x, vv.x) + 0.7f * xv[4 * j + 0];
    r.y = bnrelu(acc[j].y, g.y, be.y, m.y, vv.y) + 0.7f * xv[4 * j + 1];
    r.z = bnrelu(acc[j].z, g.z, be.z, m.z, vv.z) + 0.7f * xv[4 * j + 2];
    r.w = bnrelu(acc[j].w, g.w, be.w, m.w, vv.w) + 0.7f * xv[4 * j + 3];
    float4 ep = *(const float4*)(emb + (size_t)i * HDIM + 4 * j);
    float4 en = make_float4(ep.x + wi * r.x, ep.y + wi * r.y, ep.z + wi * r.z, ep.w + wi * r.w);
    if (!last) {
      *(float4*)(x + (size_t)i * HDIM + 4 * j) = r;
      *(float4*)(emb + (size_t)i * HDIM + 4 * j) = en;
    } else {
      float4 wa = *(const float4*)(ow + 4 * j);
      float4 wb = *(const float4*)(ow + 20 + 4 * j);
      o0 += en.x * wa.x + en.y * wa.y + en.z * wa.z + en.w * wa.w;
      o1 += en.x * wb.x + en.y * wb.y + en.z * wb.z + en.w * wb.w;
    }
  }
  if (last) {
    dout[(size_t)i * 2 + 0] = o0 + ob[0];
    dout[(size_t)i * 2 + 1] = o1 + ob[1];
  }
}

// ---------------- launch ----------------

extern "C" void kernel_launch(void* const* d_in, const int* in_sizes, int n_in,
                              void* d_out, int out_size, void* d_ws, size_t ws_size,
                              hipStream_t stream) {
  const float* feat = (const float*)d_in[0];
  const int* edges = (const int*)d_in[1];
  const float* W0 = (const float*)d_in[3];
  const float* b0 = (const float*)d_in[4];
  const float* W1 = (const float*)d_in[5];
  const float* b1 = (const float*)d_in[6];
  const float* W2 = (const float*)d_in[7];
  const float* b2 = (const float*)d_in[8];
  const float* W3 = (const float*)d_in[9];
  const float* b3 = (const float*)d_in[10];
  const float* bg = (const float*)d_in[11];
  const float* bb = (const float*)d_in[12];
  const float* bm = (const float*)d_in[13];
  const float* bv = (const float*)d_in[14];
  const float* fw = (const float*)d_in[15];
  const float* ow = (const float*)d_in[16];
  const float* ob = (const float*)d_in[17];

  int N = in_sizes[0] / IN_DIM;
  int E = in_sizes[1] / 2;
  const int* src = edges;
  const int* dst = edges + E;

  // workspace layout
  float* dis = (float*)d_ws;                 // N
  int* cnt = (int*)(dis + N);                // N
  int* scanned = cnt + N;                    // N
  int* bsums = scanned + N;                  // 1024
  int* rowptr = bsums + 1024;                // N+1
  int* cursor = rowptr + N + 1;              // N
  uintptr_t p = (uintptr_t)(cursor + N);
  p = (p + 15) & ~(uintptr_t)15;
  int2* csr = (int2*)p;                      // E
  float* Y = (float*)(csr + E);              // N x 64
  float* S1 = Y + (size_t)N * 64;            // N x 20
  float* S2 = S1 + (size_t)N * HDIM;         // N x 20
  float* S3 = S2 + (size_t)N * HDIM;         // N x 20
  float* X = S3 + (size_t)N * HDIM;          // N x 20
  float* EMB = X + (size_t)N * HDIM;         // N x 20

  const int tb = 256;
  int gE = (E + tb - 1) / tb;
  int gN = (N + tb - 1) / tb;
  int nb = (N + SCAN_BS - 1) / SCAN_BS;
  int gP5 = (N * 5 + 319) / 320;
  int gP10 = (N * 10 + 319) / 320;

  // degrees (src->deg float, dst->cnt int) in one edge pass
  hipMemsetAsync(dis, 0, (size_t)N * 4, stream);
  hipMemsetAsync(cnt, 0, (size_t)N * 4, stream);
  count_both<<<gE, tb, 0, stream>>>(src, dst, dis, cnt, E);
  make_dis<<<gN, tb, 0, stream>>>(dis, N);

  // CSR by dst
  scan1<<<nb, SCAN_BS, 0, stream>>>(cnt, scanned, bsums, N);
  scan2<<<1, SCAN_BS, 0, stream>>>(bsums, nb);
  scan3<<<gN, tb, 0, stream>>>(scanned, bsums, cnt, rowptr, cursor, N);
  place_edges<<<gE, tb, 0, stream>>>(src, dst, dis, cursor, csr, E);

  // layer 0
  gemm0<<<(N + 127) / 128, 256, 0, stream>>>(feat, W0, Y, N);
  prop40_csr<<<gP10, 320, 0, stream>>>(Y, rowptr, csr, S1, S2, N);
  prop20_csr<<<gP5, 320, 0, stream>>>(S2, rowptr, csr, S3, N);
  layer0_fused<<<gN, tb, 0, stream>>>(Y, S1, S3, b0, bg, bb, bm, bv, fw, X, EMB, N);

  // layers 1..3
  const float* Ws[3] = {W1, W2, W3};
  const float* bs[3] = {b1, b2, b3};
  for (int i = 1; i <= 3; i++) {
    prop20_csr<<<gP5, 320, 0, stream>>>(X, rowptr, csr, S1, N);
    prop20_csr<<<gP5, 320, 0, stream>>>(S1, rowptr, csr, S2, N);
    layer_fused<<<gN, tb, 0, stream>>>(Ws[i - 1], bs[i - 1], bg + i * HDIM, bb + i * HDIM,
                                       bm + i * HDIM, bv + i * HDIM, fw, i, S1, S2, X, EMB,
                                       ow, ob, (float*)d_out, (i == 3) ? 1 : 0, N);
  }
}